// Round 4
// baseline (919.852 us; speedup 1.0000x reference)
//
#include <hip/hip_runtime.h>
#include <hip/hip_bf16.h>
#include <math.h>

// Round 4: VALU-slot reduction. K=32, D=128, F=256, QB=2 (64 token rows/block).
// - gelu via 1KB LDS lerp table (err <= ~6e-4, moves work to DS pipe)
// - embed+LN merged (one pass, stats in-register)
// - GEMM1 as round 3; GEMM2 operand-swapped -> h2^T[d][tok] (contig pooling reads)
// - head MLP via MFMA (rows 2-15 garbage, ignored)
// - all f32->bf16 via v_cvt_pk (__float22bfloat162_rn)
#define KN 32
#define DD 128
#define FF 256
#define QB 2
#define MROWS 64
#define HP 136      // hln pitch (ushort): [64][136]
#define XP 264      // x pitch (ushort):   [64][264]
#define H2P 72      // h2^T pitch (ushort): [128][72]  (144B rows, 16B-aligned)
#define PLP 264     // plnb pitch (ushort): [16][264]

typedef __attribute__((ext_vector_type(8))) short bf16x8;
typedef __attribute__((ext_vector_type(4))) float f32x4;

__device__ __forceinline__ unsigned short f2bf(float x) {
    union { float f; unsigned u; } c; c.f = x;
    unsigned r = c.u + 0x7fffu + ((c.u >> 16) & 1u);
    return (unsigned short)(r >> 16);
}
__device__ __forceinline__ float bfbits2f(unsigned bits) {   // bits already in high half
    union { unsigned u; float f; } c; c.u = bits;
    return c.f;
}
__device__ __forceinline__ unsigned pk2bf(float a, float b) {
    union { __hip_bfloat162 h2; unsigned u; } c;
    c.h2 = __float22bfloat162_rn(float2{a, b});
    return c.u;
}
// exact-ish gelu (A&S 7.1.26 erf, |err|<=1.5e-7) — prep + head epilogue only
__device__ __forceinline__ float gelu_exact(float x) {
    float z  = __builtin_fabsf(x) * 0.70710678118654752440f;
    float e  = __builtin_amdgcn_exp2f(z * z * -1.4426950408889634f);
    float t  = __builtin_amdgcn_rcpf(fmaf(0.3275911f, z, 1.0f));
    float p  = fmaf(1.061405429f, t, -1.453152027f);
    p = fmaf(p, t, 1.421413741f);
    p = fmaf(p, t, -0.284496736f);
    p = fmaf(p, t, 0.254829592f);
    p = p * t;
    float erfz = fmaf(-p, e, 1.0f);
    float erfs = (x < 0.0f) ? -erfz : erfz;
    float hx = 0.5f * x;
    return fmaf(hx, erfs, hx);
}
// LDS lerp gelu: 128 intervals on [-4,4]; x>4 -> x; x<-4 -> gelu(-4)~ -1.3e-4
__device__ __forceinline__ float gelu_lut(float x, const float2* __restrict__ tbl) {
    float xc = fminf(fmaxf(x, -4.0f), 4.0f);
    float tf = fmaf(xc, 16.0f, 64.0f);          // [0,128]
    int   i  = (int)tf;
    i = (i > 127) ? 127 : i;
    float fr = tf - (float)i;
    float2 p = tbl[i];
    float v  = fmaf(fr, p.y - p.x, p.x);
    return (x > 4.0f) ? x : v;
}

// Prep: w1/w2 -> bf16 (natural), hw1 -> bf16 (natural), gelu table (128 float2).
__global__ void prep_kernel(const float* __restrict__ w1,
                            const float* __restrict__ w2,
                            const float* __restrict__ hw1,
                            unsigned short* __restrict__ w1b,
                            unsigned short* __restrict__ w2b,
                            unsigned short* __restrict__ hw1b,
                            float2* __restrict__ tblg) {
    int i = blockIdx.x * 256 + threadIdx.x;   // 0..65535
    if (i < 32768) { w1b[i] = f2bf(w1[i]); w2b[i] = f2bf(w2[i]); }
    hw1b[i] = f2bf(hw1[i]);
    if (i < 128) {
        float x0 = fmaf((float)i, 0.0625f, -4.0f);
        tblg[i] = float2{gelu_exact(x0), gelu_exact(x0 + 0.0625f)};
    }
}

__launch_bounds__(256, 3)
__global__ void ff_mfma_kernel(
    const float* __restrict__ xyt_q,
    const float* __restrict__ obs_coords,
    const float* __restrict__ obs_vals,
    const int*   __restrict__ nb_idx,
    const float* __restrict__ log_gammas,
    const float* __restrict__ w_in,   // [128,4]
    const float* __restrict__ b_in,
    const float* __restrict__ ln1_g,
    const float* __restrict__ ln1_b,
    const unsigned short* __restrict__ w1b,  // [256,128] bf16
    const float* __restrict__ b1,
    const unsigned short* __restrict__ w2b,  // [128,256] bf16
    const float* __restrict__ b2,
    const float* __restrict__ hln_g,
    const float* __restrict__ hln_b,
    const unsigned short* __restrict__ hw1b, // [256,256] bf16
    const float* __restrict__ hb1,
    const float* __restrict__ hw2,
    const float* __restrict__ hb2,
    const float2* __restrict__ tblg,         // 128-entry gelu table
    float* __restrict__ out)
{
    __shared__ __align__(16) unsigned short s_u[9216];       // 18432 B: hln[64][136] then h2T[128][72]
    __shared__ __align__(16) unsigned char  s_big[33792];    // x[64][264] then pool/plnb/hd
    __shared__ __align__(16) float s_tokf[MROWS][4];
    __shared__ __align__(16) float2 s_tbl[128];
    __shared__ float s_mu[QB], s_sig[QB];
    __shared__ float s_red[4][QB];

    const int t    = threadIdx.x;
    const int lane = t & 63;
    const int wv   = t >> 6;
    const int m16  = lane & 15;
    const int quad = lane >> 4;
    const int q0   = blockIdx.x * QB;

    unsigned short* s_hA   = s_u;                              // [64][HP]
    unsigned short* h2T    = s_u;                              // [128][H2P]
    unsigned short* s_x    = (unsigned short*)s_big;           // [64][XP]
    float*          s_pool = (float*)s_big;                    // [2][256]
    unsigned short* s_plnb = (unsigned short*)(s_big + 2048);  // [16][PLP] (rows 2-15 garbage)
    float*          s_hd   = (float*)(s_big + 10496);          // [2][256]

    // ---- table load + Phase 0: gather, tokens, mu/sigma ----
    if (t < 128) s_tbl[t] = tblg[t];
    if (t < MROWS) {
        int qi = t >> 5, j = t & 31;
        int q = q0 + qi;
        int idx = nb_idx[q * KN + j];
        float v = obs_vals[idx];
        float g0 = expf(log_gammas[0]), g1 = expf(log_gammas[1]), g2 = expf(log_gammas[2]);
        s_tokf[t][0] = (obs_coords[idx * 3 + 0] - xyt_q[q * 3 + 0]) * g0;
        s_tokf[t][1] = (obs_coords[idx * 3 + 1] - xyt_q[q * 3 + 1]) * g1;
        s_tokf[t][2] = (obs_coords[idx * 3 + 2] - xyt_q[q * 3 + 2]) * g2;
        float s = v, ss = v * v;
        #pragma unroll
        for (int m = 1; m < 32; m <<= 1) {
            s  += __shfl_xor(s, m);
            ss += __shfl_xor(ss, m);
        }
        float mu  = s * (1.0f / KN);
        float var = (ss - (float)KN * mu * mu) * (1.0f / (KN - 1));
        float sig = fmaxf(sqrtf(fmaxf(var, 0.0f)), 1e-3f);
        if (j == 0) { s_mu[qi] = mu; s_sig[qi] = sig; }
        s_tokf[t][3] = (v - mu) / sig;
    }
    __syncthreads();

    // ---- Phase 1 (merged embed + LN): wave handles tokens wv*16..+15;
    //      lane owns dims {2*lane, 2*lane+1}; stats via 64-lane butterfly ----
    {
        const float4 wlo = ((const float4*)w_in)[2 * lane];
        const float4 whi = ((const float4*)w_in)[2 * lane + 1];
        const float2 bb  = *(const float2*)&b_in[2 * lane];
        const float2 gg  = *(const float2*)&ln1_g[2 * lane];
        const float2 cc  = *(const float2*)&ln1_b[2 * lane];
        for (int i = 0; i < 16; i++) {
            int tok = wv * 16 + i;
            float4 tk = *(const float4*)&s_tokf[tok][0];
            float a0 = fmaf(wlo.x, tk.x, fmaf(wlo.y, tk.y, fmaf(wlo.z, tk.z, fmaf(wlo.w, tk.w, bb.x))));
            float a1 = fmaf(whi.x, tk.x, fmaf(whi.y, tk.y, fmaf(whi.z, tk.z, fmaf(whi.w, tk.w, bb.y))));
            float v0 = gelu_lut(a0, s_tbl);
            float v1 = gelu_lut(a1, s_tbl);
            float s = v0 + v1, ss = v0 * v0 + v1 * v1;
            #pragma unroll
            for (int m = 1; m < 64; m <<= 1) {
                s  += __shfl_xor(s, m);
                ss += __shfl_xor(ss, m);
            }
            float mean = s * (1.0f / DD);
            float var  = ss * (1.0f / DD) - mean * mean;
            float rstd = rsqrtf(fmaxf(var, 0.0f) + 1e-5f);
            float y0 = fmaf((v0 - mean) * rstd, gg.x, cc.x);
            float y1 = fmaf((v1 - mean) * rstd, gg.y, cc.y);
            *(unsigned*)&s_hA[tok * HP + 2 * lane] = pk2bf(y0, y1);
        }
    }
    __syncthreads();

    // ---- Phase 3: MFMA GEMM1  x[tok][F] = gelu(hln @ w1^T + b1); wave strip F in [wv*64,+64) ----
    {
        bf16x8 B[4][4];
        #pragma unroll
        for (int ct = 0; ct < 4; ct++)
            #pragma unroll
            for (int kk = 0; kk < 4; kk++)
                B[ct][kk] = *(const bf16x8*)&w1b[(wv * 64 + ct * 16 + m16) * 128 + kk * 32 + quad * 8];
        #pragma unroll
        for (int rt = 0; rt < 4; rt++) {
            bf16x8 A[4];
            #pragma unroll
            for (int kk = 0; kk < 4; kk++)
                A[kk] = *(const bf16x8*)&s_hA[(rt * 16 + m16) * HP + kk * 32 + quad * 8];
            #pragma unroll
            for (int ct = 0; ct < 4; ct++) {
                f32x4 acc = {0.f, 0.f, 0.f, 0.f};
                #pragma unroll
                for (int kk = 0; kk < 4; kk++)
                    acc = __builtin_amdgcn_mfma_f32_16x16x32_bf16(A[kk], B[ct][kk], acc, 0, 0, 0);
                int col = wv * 64 + ct * 16 + m16;
                float bb = b1[col];
                float g0v = gelu_lut(acc[0] + bb, s_tbl);
                float g1v = gelu_lut(acc[1] + bb, s_tbl);
                float g2v = gelu_lut(acc[2] + bb, s_tbl);
                float g3v = gelu_lut(acc[3] + bb, s_tbl);
                unsigned p01 = pk2bf(g0v, g1v), p23 = pk2bf(g2v, g3v);
                int r0 = rt * 16 + quad * 4;
                s_x[(r0 + 0) * XP + col] = (unsigned short)(p01 & 0xffffu);
                s_x[(r0 + 1) * XP + col] = (unsigned short)(p01 >> 16);
                s_x[(r0 + 2) * XP + col] = (unsigned short)(p23 & 0xffffu);
                s_x[(r0 + 3) * XP + col] = (unsigned short)(p23 >> 16);
            }
        }
    }
    __syncthreads();

    // ---- Phase 4 (swapped): h2T[d][tok] = gelu(w2 @ x^T + b2); A=w2 rows d, B=x rows tok ----
    {
        #pragma unroll
        for (int mt = 0; mt < 2; mt++) {
            int dbase = (wv * 2 + mt) * 16;
            bf16x8 A2[8];
            #pragma unroll
            for (int kk = 0; kk < 8; kk++)
                A2[kk] = *(const bf16x8*)&w2b[(dbase + m16) * 256 + kk * 32 + quad * 8];
            float bb0 = b2[dbase + quad * 4 + 0];
            float bb1 = b2[dbase + quad * 4 + 1];
            float bb2 = b2[dbase + quad * 4 + 2];
            float bb3 = b2[dbase + quad * 4 + 3];
            #pragma unroll
            for (int nt = 0; nt < 4; nt++) {
                f32x4 acc = {0.f, 0.f, 0.f, 0.f};
                #pragma unroll
                for (int kk = 0; kk < 8; kk++) {
                    bf16x8 Bf = *(const bf16x8*)&s_x[(nt * 16 + m16) * XP + kk * 32 + quad * 8];
                    acc = __builtin_amdgcn_mfma_f32_16x16x32_bf16(A2[kk], Bf, acc, 0, 0, 0);
                }
                float g0v = gelu_lut(acc[0] + bb0, s_tbl);
                float g1v = gelu_lut(acc[1] + bb1, s_tbl);
                float g2v = gelu_lut(acc[2] + bb2, s_tbl);
                float g3v = gelu_lut(acc[3] + bb3, s_tbl);
                unsigned p01 = pk2bf(g0v, g1v), p23 = pk2bf(g2v, g3v);
                int tok = nt * 16 + m16;
                int d0 = dbase + quad * 4;
                h2T[(d0 + 0) * H2P + tok] = (unsigned short)(p01 & 0xffffu);
                h2T[(d0 + 1) * H2P + tok] = (unsigned short)(p01 >> 16);
                h2T[(d0 + 2) * H2P + tok] = (unsigned short)(p23 & 0xffffu);
                h2T[(d0 + 3) * H2P + tok] = (unsigned short)(p23 >> 16);
            }
        }
    }
    __syncthreads();

    // ---- Phase 5: pool mean/max over K=32 (contiguous b128 reads of h2T rows) ----
    {
        int d = t & 127, qi = t >> 7;
        const uint4* rp = (const uint4*)&h2T[d * H2P + qi * 32];
        float sm = 0.f, mx = -INFINITY;
        #pragma unroll
        for (int j = 0; j < 4; j++) {
            uint4 u4 = rp[j];
            unsigned uu[4] = {u4.x, u4.y, u4.z, u4.w};
            #pragma unroll
            for (int e = 0; e < 4; e++) {
                float lo = bfbits2f(uu[e] << 16);
                float hi = bfbits2f(uu[e] & 0xffff0000u);
                sm += lo + hi;
                mx = fmaxf(mx, fmaxf(lo, hi));
            }
        }
        s_pool[qi * 256 + d]       = sm * (1.0f / KN);
        s_pool[qi * 256 + 128 + d] = mx;
    }
    __syncthreads();

    // ---- Phase 6: head LN over 256 -> bf16 s_plnb rows 0..1 ----
    if (t < 128) {
        int qi = t >> 6, l = t & 63;
        float v0 = s_pool[qi * 256 + l],       v1 = s_pool[qi * 256 + l + 64];
        float v2 = s_pool[qi * 256 + l + 128], v3 = s_pool[qi * 256 + l + 192];
        float s = v0 + v1 + v2 + v3;
        float ss = v0 * v0 + v1 * v1 + v2 * v2 + v3 * v3;
        #pragma unroll
        for (int m = 1; m < 64; m <<= 1) {
            s  += __shfl_xor(s, m);
            ss += __shfl_xor(ss, m);
        }
        float mean = s * (1.0f / (2 * DD));
        float var  = ss * (1.0f / (2 * DD)) - mean * mean;
        float rstd = rsqrtf(fmaxf(var, 0.0f) + 1e-5f);
        s_plnb[qi * PLP + l]       = f2bf((v0 - mean) * rstd * hln_g[l]       + hln_b[l]);
        s_plnb[qi * PLP + l + 64]  = f2bf((v1 - mean) * rstd * hln_g[l + 64]  + hln_b[l + 64]);
        s_plnb[qi * PLP + l + 128] = f2bf((v2 - mean) * rstd * hln_g[l + 128] + hln_b[l + 128]);
        s_plnb[qi * PLP + l + 192] = f2bf((v3 - mean) * rstd * hln_g[l + 192] + hln_b[l + 192]);
    }
    __syncthreads();

    // ---- Phase 7a: head GEMM via MFMA; A rows 0/1 = queries (2-15 garbage, ignored) ----
    {
        bf16x8 Ah[8];
        #pragma unroll
        for (int kk = 0; kk < 8; kk++)
            Ah[kk] = *(const bf16x8*)&s_plnb[m16 * PLP + kk * 32 + quad * 8];
        #pragma unroll
        for (int ct = 0; ct < 4; ct++) {
            int f = wv * 64 + ct * 16 + m16;
            f32x4 acc = {0.f, 0.f, 0.f, 0.f};
            #pragma unroll
            for (int kk = 0; kk < 8; kk++) {
                bf16x8 Bf = *(const bf16x8*)&hw1b[f * 256 + kk * 32 + quad * 8];
                acc = __builtin_amdgcn_mfma_f32_16x16x32_bf16(Ah[kk], Bf, acc, 0, 0, 0);
            }
            if (quad == 0) {
                s_hd[f]       = acc[0];   // query 0
                s_hd[256 + f] = acc[1];   // query 1
            }
        }
    }
    __syncthreads();

    // ---- Phase 7b: gelu + dot(hw2) + reduce ----
    {
        float a0 = s_hd[t]       + hb1[t];
        float a1 = s_hd[256 + t] + hb1[t];
        float hv = hw2[t];
        float c0 = gelu_exact(a0) * hv;
        float c1 = gelu_exact(a1) * hv;
        #pragma unroll
        for (int m = 1; m < 64; m <<= 1) {
            c0 += __shfl_xor(c0, m);
            c1 += __shfl_xor(c1, m);
        }
        if (lane == 0) { s_red[wv][0] = c0; s_red[wv][1] = c1; }
    }
    __syncthreads();
    if (t == 0) {
        float u0 = s_red[0][0] + s_red[1][0] + s_red[2][0] + s_red[3][0] + hb2[0];
        float u1 = s_red[0][1] + s_red[1][1] + s_red[2][1] + s_red[3][1] + hb2[0];
        out[q0 + 0] = u0 * s_sig[0] + s_mu[0];
        out[q0 + 1] = u1 * s_sig[1] + s_mu[1];
    }
}

extern "C" void kernel_launch(void* const* d_in, const int* in_sizes, int n_in,
                              void* d_out, int out_size, void* d_ws, size_t ws_size,
                              hipStream_t stream)
{
    const float* xyt_q      = (const float*)d_in[0];
    const float* obs_coords = (const float*)d_in[1];
    const float* obs_vals   = (const float*)d_in[2];
    const int*   nb_idx     = (const int*)d_in[3];
    const float* log_gammas = (const float*)d_in[4];
    const float* w_in  = (const float*)d_in[5];
    const float* b_in  = (const float*)d_in[6];
    const float* ln1_g = (const float*)d_in[7];
    const float* ln1_b = (const float*)d_in[8];
    const float* w1    = (const float*)d_in[9];
    const float* b1    = (const float*)d_in[10];
    const float* w2    = (const float*)d_in[11];
    const float* b2    = (const float*)d_in[12];
    const float* hln_g = (const float*)d_in[13];
    const float* hln_b = (const float*)d_in[14];
    const float* hw1   = (const float*)d_in[15];
    const float* hb1   = (const float*)d_in[16];
    const float* hw2   = (const float*)d_in[17];
    const float* hb2   = (const float*)d_in[18];
    float* out = (float*)d_out;

    const int Q = in_sizes[0] / 3;   // 32768

    // ws: w1b 64K | w2b 64K | hw1b 128K | gelu table 1K
    unsigned short* w1b  = (unsigned short*)d_ws;
    unsigned short* w2b  = w1b + 32768;
    unsigned short* hw1b = (unsigned short*)((char*)d_ws + 131072);
    float2*         tblg = (float2*)((char*)d_ws + 262144);

    prep_kernel<<<256, 256, 0, stream>>>(w1, w2, hw1, w1b, w2b, hw1b, tblg);

    ff_mfma_kernel<<<Q / QB, 256, 0, stream>>>(
        xyt_q, obs_coords, obs_vals, nb_idx, log_gammas,
        w_in, b_in, ln1_g, ln1_b,
        w1b, b1, w2b, b2,
        hln_g, hln_b, hw1b, hb1, hw2, hb2, tblg, out);
}